// Round 14
// baseline (159.478 us; speedup 1.0000x reference)
//
#include <hip/hip_runtime.h>
#include <hip/hip_bf16.h>
#include <cstdint>

#define SEQ   720
#define PRED  720
#define CH    862
#define NB    64
#define NIN   360   // IN_LEN
#define KP    384   // padded K (12 * 32)
#define CP    896   // padded channels (7 * 128)
#define PP    768   // padded pred (6 * 128)
#define BK    32
#define NPT   12    // p-tiles of 64

typedef __attribute__((ext_vector_type(8))) short s16x8;
typedef __attribute__((ext_vector_type(4))) float f32x4;
typedef __attribute__((ext_vector_type(2))) float f32x2;
typedef unsigned int u32;
typedef unsigned short u16;

__device__ __forceinline__ u16 to_bf16u(float f){
  __hip_bfloat16 h = __float2bfloat16(f);
  return *reinterpret_cast<u16*>(&h);
}

// ---------------- Fused prep0: Dt_bf (DCT^T bf16) | Wlo_bf cast | Srow/Slo (R13-verified) ----------------
__global__ __launch_bounds__(256) void k_prep0(const float* __restrict__ Wlo,
                                               u16* __restrict__ Dt, u16* __restrict__ Wbf,
                                               float* __restrict__ Srow, float* __restrict__ Slo){
  int bid = blockIdx.x, t = threadIdx.x;
  if (bid < 576){
    int idx = bid*256 + t;
    int m = idx / 384, n = idx % 384;
    u16 v = 0;
    if (m < NIN && n < NIN){
      int r = ((2*m+1)*n) % (4*NIN);
      float ang = (float)r * (float)(3.14159265358979323846 / 720.0);
      float x = cosf(ang) * 0.07453559924999299f;
      if (n == 0) x *= 0.7071067811865476f;
      v = to_bf16u(x);
    }
    Dt[idx] = v;
  } else if (bid < 1728){
    int idx = (bid - 576)*256 + t;
    int p = idx / 384, n = idx % 384;
    u16 v = 0;
    if (p < PRED && n < NIN) v = to_bf16u(Wlo[(size_t)p*NIN + n]);
    Wbf[idx] = v;
  } else {
    int w = t >> 6, l = t & 63;
    int p = (bid - 1728)*4 + w;
    if (p < PRED){
      const float* row = Wlo + (size_t)p*NIN;
      float s = 0.f;
      for (int i = l; i < NIN; i += 64) s += row[i];
      #pragma unroll
      for (int off = 32; off > 0; off >>= 1) s += __shfl_down(s, off);
      if (l == 0){
        Slo[p]  = s;
        Srow[p] = row[0] * 0.05270462766947299f;   // 1/sqrt(360), exact row-sum of M
      }
    }
  }
}

#define GLOAD_LDS16(gp, lp_) __builtin_amdgcn_global_load_lds( \
    (const __attribute__((address_space(1))) u32*)(gp), \
    (__attribute__((address_space(3))) u32*)(lp_), 16, 0, 0)

// ---------------- k_mgemm: Mbf = bf16( Wlo_bf x Dt_bf^T / 360 ) (R13-verified) ----------------
__global__ __launch_bounds__(256, 4) void k_mgemm(const u16* __restrict__ Wbf, const u16* __restrict__ Dt,
                                                  u16* __restrict__ Mbf){
  int bid = blockIdx.x;
  int pt = bid % 6;
  int mt = bid / 6;

  int t  = threadIdx.x;
  int w  = t >> 6, l = t & 63;
  int wr = w >> 1, wc = w & 1;

  __shared__ __align__(16) char smem[32768];
  u16 (*As)[128*BK] = reinterpret_cast<u16(*)[128*BK]>(smem);
  u16 (*Bs)[128*BK] = reinterpret_cast<u16(*)[128*BK]>(smem + 16384);
  float (*wb2)[132] = reinterpret_cast<float(*)[132]>(smem);

  f32x4 acc[4][4] = {};

  const u16* Abase = Wbf + (size_t)pt*128*KP;
  const u16* Bbase = Dt + (size_t)mt*128*KP;
  int srow = t >> 2;
  int squad = t & 3;
  int row16 = l & 15, kb = l >> 4;
  int sperm = (srow >> 1) & 3;
  int rperm = (row16 >> 1) & 3;

#define STAGEM(bufi, k0) do { \
    GLOAD_LDS16(Abase + (size_t)(srow)*KP + (k0) + ((squad^sperm))*8,      &As[bufi][(srow)*BK + squad*8]); \
    GLOAD_LDS16(Abase + (size_t)(64 + srow)*KP + (k0) + ((squad^sperm))*8, &As[bufi][(64 + srow)*BK + squad*8]); \
    GLOAD_LDS16(Bbase + (size_t)(srow)*KP + (k0) + ((squad^sperm))*8,      &Bs[bufi][(srow)*BK + squad*8]); \
    GLOAD_LDS16(Bbase + (size_t)(64 + srow)*KP + (k0) + ((squad^sperm))*8, &Bs[bufi][(64 + srow)*BK + squad*8]); \
  } while(0)

  STAGEM(0, 0);
  for (int ks = 0; ks < 12; ks++){
    int cur = ks & 1;
    if (ks < 11){
      STAGEM(cur ^ 1, (ks + 1) * BK);
      asm volatile("s_waitcnt vmcnt(4)" ::: "memory");
    } else {
      asm volatile("s_waitcnt vmcnt(0)" ::: "memory");
    }
    __builtin_amdgcn_s_barrier();
    const u16* aB = &As[cur][(wr*64 + row16)*BK + (kb^rperm)*8];
    const u16* bB = &Bs[cur][(wc*64 + row16)*BK + (kb^rperm)*8];
    s16x8 bfr[4];
    #pragma unroll
    for (int ni = 0; ni < 4; ni++)
      bfr[ni] = *reinterpret_cast<const s16x8*>(bB + ni*16*BK);
    #pragma unroll
    for (int mi = 0; mi < 4; mi++){
      s16x8 af = *reinterpret_cast<const s16x8*>(aB + mi*16*BK);
      #pragma unroll
      for (int ni = 0; ni < 4; ni++)
        acc[mi][ni] = __builtin_amdgcn_mfma_f32_16x16x32_bf16(af, bfr[ni], acc[mi][ni], 0, 0, 0);
    }
    __builtin_amdgcn_s_barrier();
  }
  __syncthreads();

  const float inv360 = 1.0f/360.0f;
  #pragma unroll 1
  for (int mi = 0; mi < 4; mi++){
    #pragma unroll
    for (int ni = 0; ni < 4; ni++)
      #pragma unroll
      for (int r = 0; r < 4; r++)
        wb2[wr*16 + kb*4 + r][wc*64 + ni*16 + row16] = acc[mi][ni][r];
    __syncthreads();
    #pragma unroll
    for (int it = 0; it < 2; it++){
      int wi = it*256 + t;
      int rl = wi >> 4, seg = wi & 15;
      int p = pt*128 + (rl>>4)*64 + mi*16 + (rl & 15);
      f32x4 g0 = *reinterpret_cast<const f32x4*>(&wb2[rl][seg*8]);
      f32x4 g1 = *reinterpret_cast<const f32x4*>(&wb2[rl][seg*8 + 4]);
      uint4 pk;
      pk.x = (u32)to_bf16u(g0.x*inv360) | ((u32)to_bf16u(g0.y*inv360) << 16);
      pk.y = (u32)to_bf16u(g0.z*inv360) | ((u32)to_bf16u(g0.w*inv360) << 16);
      pk.z = (u32)to_bf16u(g1.x*inv360) | ((u32)to_bf16u(g1.y*inv360) << 16);
      pk.w = (u32)to_bf16u(g1.z*inv360) | ((u32)to_bf16u(g1.w*inv360) << 16);
      *reinterpret_cast<uint4*>(&Mbf[(size_t)p*KP + mt*128 + seg*8]) = pk;
    }
    __syncthreads();
  }
}

// ---------------- Kernel C: pair sums -> bf16 A-matrix, two 192-row halves (R10-verified) ----------------
__global__ __launch_bounds__(256) void k_pre(const float* __restrict__ x, u16* __restrict__ pairB,
                                             float* __restrict__ meanw){
  int b  = blockIdx.y;
  int c0 = blockIdx.x * 64;
  int t  = threadIdx.x;
  int c16  = t & 15;
  int mrow = t >> 4;
  int w    = t >> 6;
  __shared__ u16  pl[192][66];
  __shared__ float red[4][64];
  const float rs2 = 0.7071067811865476f;
  int cb = c0 + c16*4;
  bool full = (cb + 3 < CH);
  const float* xb = x + (size_t)b*SEQ*CH + cb;
  float s0=0.f, s1=0.f, s2=0.f, s3=0.f;
  int rowc = t >> 2;
  int mq0  = t & 3;
  size_t rbase = ((size_t)b*CP + c0 + rowc) * KP;

  #pragma unroll 1
  for (int h = 0; h < 2; h++){
    #pragma unroll 1
    for (int ml = mrow; ml < 192; ml += 16){
      int m = h*192 + ml;
      float p0=0.f, p1=0.f, p2=0.f, p3=0.f;
      if (m < NIN){
        const float* r0 = xb + (size_t)(2*m)*CH;
        float a0,a1,a2,a3, e0,e1,e2,e3;
        if (full){
          f32x4 va = *reinterpret_cast<const f32x4*>(r0);
          f32x2 vb = *reinterpret_cast<const f32x2*>(r0 + CH);
          f32x2 vc = *reinterpret_cast<const f32x2*>(r0 + CH + 2);
          a0=va.x; a1=va.y; a2=va.z; a3=va.w;
          e0=vb.x; e1=vb.y; e2=vc.x; e3=vc.y;
        } else {
          a0 = (cb+0<CH)? r0[0]:0.f; a1 = (cb+1<CH)? r0[1]:0.f;
          a2 = (cb+2<CH)? r0[2]:0.f; a3 = (cb+3<CH)? r0[3]:0.f;
          e0 = (cb+0<CH)? r0[CH+0]:0.f; e1 = (cb+1<CH)? r0[CH+1]:0.f;
          e2 = (cb+2<CH)? r0[CH+2]:0.f; e3 = (cb+3<CH)? r0[CH+3]:0.f;
        }
        p0=a0+e0; p1=a1+e1; p2=a2+e2; p3=a3+e3;
        s0+=p0; s1+=p1; s2+=p2; s3+=p3;
      }
      u32 lo = (u32)to_bf16u(p0*rs2) | ((u32)to_bf16u(p1*rs2) << 16);
      u32 hi = (u32)to_bf16u(p2*rs2) | ((u32)to_bf16u(p3*rs2) << 16);
      *reinterpret_cast<u32*>(&pl[ml][c16*4 + 0]) = lo;
      *reinterpret_cast<u32*>(&pl[ml][c16*4 + 2]) = hi;
    }
    __syncthreads();
    #pragma unroll
    for (int i = 0; i < 6; i++){
      int mg = mq0 + 4*i;
      u16 vals[8];
      #pragma unroll
      for (int j = 0; j < 8; j++) vals[j] = pl[mg*8 + j][rowc];
      uint4 pk;
      pk.x = (u32)vals[0] | ((u32)vals[1] << 16);
      pk.y = (u32)vals[2] | ((u32)vals[3] << 16);
      pk.z = (u32)vals[4] | ((u32)vals[5] << 16);
      pk.w = (u32)vals[6] | ((u32)vals[7] << 16);
      *reinterpret_cast<uint4*>(pairB + rbase + h*192 + (size_t)mg*8) = pk;
    }
    __syncthreads();
  }

  s0 += __shfl_down(s0, 32); s1 += __shfl_down(s1, 32);
  s2 += __shfl_down(s2, 32); s3 += __shfl_down(s3, 32);
  s0 += __shfl_down(s0, 16); s1 += __shfl_down(s1, 16);
  s2 += __shfl_down(s2, 16); s3 += __shfl_down(s3, 16);
  if ((t & 63) < 16){
    f32x4 rv; rv.x=s0; rv.y=s1; rv.z=s2; rv.w=s3;
    *reinterpret_cast<f32x4*>(&red[w][c16*4]) = rv;
  }
  __syncthreads();
  if (t < 64){
    float mean = (red[0][t] + red[1][t] + red[2][t] + red[3][t]) * (1.0f/SEQ);
    meanw[(size_t)b*CP + c0 + t] = mean;
  }
}

// ---------------- Kernel D: GEMM, 128c x 64p tiles for occupancy (R8 schedule kept) ----------------
// Block = (b, ct, pt64). 4 waves; wave w owns c-rows [w*32, w*32+32) x all 64 p.
// acc = 32 AGPR/wave; LDS = As 2x8K + Bs 2x4K = 24 KB -> target 5-6 blocks/CU.
__global__ __launch_bounds__(256, 5) void k_gemm(const u16* __restrict__ Apack, const u16* __restrict__ Mbf,
                                              const float* __restrict__ Srow, const float* __restrict__ Slo,
                                              const float* __restrict__ meanw,
                                              const float* __restrict__ w1, const float* __restrict__ b1,
                                              const float* __restrict__ w2, const float* __restrict__ b2,
                                              const float* __restrict__ blo,
                                              float* __restrict__ out){
  // XCD swizzle: 5376 = 8*672; 12 consecutive idx share (b,ct) A-panel on one XCD.
  int bid = blockIdx.x;
  int idx = (bid & 7) * 672 + (bid >> 3);
  int pt  = idx % NPT;
  int rem = idx / NPT;
  int ct  = rem % 7;
  int b   = rem / 7;

  int t  = threadIdx.x;
  int w  = t >> 6, l = t & 63;

  __shared__ __align__(16) char smem[24576];
  u16 (*As)[128*BK] = reinterpret_cast<u16(*)[128*BK]>(smem);           // 2 x 8 KB
  u16 (*Bs)[64*BK]  = reinterpret_cast<u16(*)[64*BK]>(smem + 16384);    // 2 x 4 KB
  float (*wbuf)[132] = reinterpret_cast<float(*)[132]>(smem);           // epilogue [16][132]

  f32x4 acc[2][4] = {};

  const u16* Abase = Apack + ((size_t)b*CP + (size_t)ct*128) * KP;
  const u16* Bbase = Mbf + (size_t)pt*64*KP;
  int srow = t >> 2;                  // 0..63
  int squad = t & 3;
  int row16 = l & 15, kb = l >> 4;
  int sperm = (srow >> 1) & 3;        // staging-row XOR key (R4-verified pair)
  int rperm = (row16 >> 1) & 3;       // read-row XOR key (same involution)

#define STAGE(bufi, k0) do { \
    GLOAD_LDS16(Abase + (size_t)(srow)*KP      + (k0) + ((squad^sperm))*8, &As[bufi][(srow)*BK + squad*8]); \
    GLOAD_LDS16(Abase + (size_t)(64 + srow)*KP + (k0) + ((squad^sperm))*8, &As[bufi][(64 + srow)*BK + squad*8]); \
    GLOAD_LDS16(Bbase + (size_t)(srow)*KP      + (k0) + ((squad^sperm))*8, &Bs[bufi][(srow)*BK + squad*8]); \
  } while(0)

  STAGE(0, 0);
  for (int ks = 0; ks < 12; ks++){
    int cur = ks & 1;
    if (ks < 11){
      STAGE(cur ^ 1, (ks + 1) * BK);
      asm volatile("s_waitcnt vmcnt(3)" ::: "memory");   // own tile's 3 loads landed
    } else {
      asm volatile("s_waitcnt vmcnt(0)" ::: "memory");
    }
    __builtin_amdgcn_s_barrier();
    const u16* aB = &As[cur][(w*32 + row16)*BK + (kb^rperm)*8];
    const u16* bB = &Bs[cur][(row16)*BK + (kb^rperm)*8];
    s16x8 bfr[4];
    #pragma unroll
    for (int nj = 0; nj < 4; nj++)
      bfr[nj] = *reinterpret_cast<const s16x8*>(bB + nj*16*BK);
    __builtin_amdgcn_s_setprio(1);
    #pragma unroll
    for (int mi = 0; mi < 2; mi++){
      s16x8 af = *reinterpret_cast<const s16x8*>(aB + mi*16*BK);
      #pragma unroll
      for (int nj = 0; nj < 4; nj++)
        acc[mi][nj] = __builtin_amdgcn_mfma_f32_16x16x32_bf16(af, bfr[nj], acc[mi][nj], 0, 0, 0);
    }
    __builtin_amdgcn_s_setprio(0);
    __builtin_amdgcn_s_barrier();
  }
  __syncthreads();   // all Bs/As reads done before wbuf aliases

  // ---- epilogue: cross-wave wbuf [16 p][128 c] -> 512 B-segment stores ----
  int c32 = t & 31;
  int cb4 = ct*128 + c32*4;
  float sc4[4], of4[4], cn4[4], bc4[4];
  #pragma unroll
  for (int j = 0; j < 4; j++){
    int c = cb4 + j;
    bool v = (c < CH);
    float w1v = v ? w1[c] : 0.f, w2v = v ? w2[c] : 0.f;
    float b1v = v ? b1[c] : 0.f, b2v = v ? b2[c] : 0.f;
    float mv  = v ? meanw[(size_t)b*CP + c] : 0.f;
    sc4[j] = 1.f + w1v*w2v;
    of4[j] = w1v*b2v + b1v;
    cn4[j] = mv;
    bc4[j] = 1.4142135623730951f * sc4[j] * mv;
  }
  bool cfull = (cb4 + 3 < CH);
  size_t outb = (size_t)b*PRED*CH;
  int prow = t >> 5;   // 0..7

  #pragma unroll
  for (int nj = 0; nj < 4; nj++){
    #pragma unroll
    for (int mi = 0; mi < 2; mi++)
      #pragma unroll
      for (int r = 0; r < 4; r++)
        wbuf[row16][w*32 + mi*16 + kb*4 + r] = acc[mi][nj][r];
    __syncthreads();
    #pragma unroll
    for (int k2 = 0; k2 < 2; k2++){
      int p_loc = k2*8 + prow;
      int p = pt*64 + nj*16 + p_loc;
      if (p < PRED){
        f32x4 g = *reinterpret_cast<const f32x4*>(&wbuf[p_loc][c32*4]);
        float sp = Srow[p], sl = Slo[p], bl = blo[p];
        f32x4 ov;
        #pragma unroll
        for (int j = 0; j < 4; j++)
          ov[j] = sc4[j]*g[j] + (cn4[j] - bc4[j]*sp + of4[j]*sl + bl);
        float* op = &out[outb + (size_t)p*CH + cb4];
        if (cfull){
          *reinterpret_cast<f32x4*>(op) = ov;
        } else {
          #pragma unroll
          for (int j = 0; j < 4; j++)
            if (cb4 + j < CH) op[j] = ov[j];
        }
      }
    }
    __syncthreads();
  }
}

extern "C" void kernel_launch(void* const* d_in, const int* in_sizes, int n_in,
                              void* d_out, int out_size, void* d_ws, size_t ws_size,
                              hipStream_t stream)
{
  const float* x   = (const float*)d_in[0];
  const float* w1  = (const float*)d_in[1];
  const float* b1  = (const float*)d_in[2];
  const float* w2  = (const float*)d_in[3];
  const float* b2  = (const float*)d_in[4];
  const float* Wlo = (const float*)d_in[5];
  const float* blo = (const float*)d_in[6];
  float* out = (float*)d_out;

  char* ws = (char*)d_ws;
  u16*   Dt    = (u16*)(ws);
  u16*   Wbf   = (u16*)(ws + 294912);
  u16*   Mbf   = (u16*)(ws + 884736);
  float* Srow  = (float*)(ws + 1474560);
  float* Slo   = (float*)(ws + 1477632);
  u16*   pairB = (u16*)(ws + 1480704);
  float* meanw = (float*)(ws + 45520896);

  k_prep0<<<dim3(1908), dim3(256), 0, stream>>>(Wlo, Dt, Wbf, Srow, Slo);
  k_mgemm<<<dim3(18), dim3(256), 0, stream>>>(Wbf, Dt, Mbf);
  k_pre<<<dim3(CP/64, NB), dim3(256), 0, stream>>>(x, pairB, meanw);
  k_gemm<<<dim3(NB*7*NPT), dim3(256), 0, stream>>>(pairB, Mbf, Srow, Slo, meanw,
                                                   w1, b1, w2, b2, blo, out);
}